// Round 1
// baseline (546.408 us; speedup 1.0000x reference)
//
#include <hip/hip_runtime.h>

// OWA pooling: 2x2 non-overlapping window, sort-descending per channel,
// weighted sum with learned kernel (4 weights).
// x: [16,224,224,128] fp32 NHWC, out: [16,112,112,128] fp32.
// Memory-bound: 411 MB read + 103 MB write, floor ~82 us at 6.3 TB/s.

#define B_  16
#define H_  224
#define W_  224
#define C_  128
#define PH_ (H_ / 2)
#define PW_ (W_ / 2)
#define C4_ (C_ / 4)           // 32 float4 per pixel
#define N4_ (B_ * PH_ * PW_ * C4_)  // total output float4 = 6,422,528

__global__ __launch_bounds__(256) void owa_pool_kernel(
    const float4* __restrict__ xin,
    const float*  __restrict__ kw,
    float4* __restrict__ out)
{
    int idx = blockIdx.x * blockDim.x + threadIdx.x;
    if (idx >= N4_) return;

    // decode output coordinate (channel-quad innermost)
    int c4 = idx & (C4_ - 1);
    int t  = idx >> 5;          // / C4_
    int pw = t % PW_;
    int t2 = t / PW_;
    int ph = t2 % PH_;
    int b  = t2 / PH_;

    const float k0 = kw[0], k1 = kw[1], k2 = kw[2], k3 = kw[3];

    // input row base in float4 units
    int row0 = ((b * H_ + 2 * ph) * W_ + 2 * pw) * C4_ + c4;
    int row1 = row0 + W_ * C4_;

    float4 v0 = xin[row0];
    float4 v1 = xin[row0 + C4_];
    float4 v2 = xin[row1];
    float4 v3 = xin[row1 + C4_];

    float4 r;
    // 4-element descending sort network (5 comparators) + weighted sum
    #define OWA_DO(comp) { \
        float a0 = v0.comp, a1 = v1.comp, a2 = v2.comp, a3 = v3.comp; \
        float hi01 = fmaxf(a0, a1), lo01 = fminf(a0, a1); \
        float hi23 = fmaxf(a2, a3), lo23 = fminf(a2, a3); \
        float s0 = fmaxf(hi01, hi23), m  = fminf(hi01, hi23); \
        float M  = fmaxf(lo01, lo23), s3 = fminf(lo01, lo23); \
        float s1 = fmaxf(m, M), s2 = fminf(m, M); \
        r.comp = k0 * s0 + k1 * s1 + k2 * s2 + k3 * s3; \
    }
    OWA_DO(x) OWA_DO(y) OWA_DO(z) OWA_DO(w)
    #undef OWA_DO

    out[idx] = r;
}

extern "C" void kernel_launch(void* const* d_in, const int* in_sizes, int n_in,
                              void* d_out, int out_size, void* d_ws, size_t ws_size,
                              hipStream_t stream) {
    const float4* xin = (const float4*)d_in[0];
    const float*  kw  = (const float*)d_in[1];
    float4* out = (float4*)d_out;

    int blocks = (N4_ + 255) / 256;
    owa_pool_kernel<<<blocks, 256, 0, stream>>>(xin, kw, out);
}

// Round 3
// 532.767 us; speedup vs baseline: 1.0256x; 1.0256x over previous
//
#include <hip/hip_runtime.h>

// OWA pooling: 2x2 non-overlapping window, per-channel descending sort,
// weighted sum with 4 learned weights.
// x: [16,224,224,128] fp32 NHWC, out: [16,112,112,128] fp32.
// Pure streaming: 411 MB read + 103 MB write, zero reuse -> HBM roofline ~82 us.
// R3: same as R2 but with clang native vector type (ext_vector_type) so
// __builtin_nontemporal_load/store compiles (HIP float4 is a class -> rejected).

typedef float vf4 __attribute__((ext_vector_type(4)));

#define B_  16
#define H_  224
#define W_  224
#define C_  128
#define PH_ (H_ / 2)
#define PW_ (W_ / 2)
#define C4_ (C_ / 4)                 // 32 float4 per pixel
#define N4_ (B_ * PH_ * PW_ * C4_)   // 6,422,528 output float4
#define PER_THREAD 2
#define STRIDE_ (N4_ / PER_THREAD)   // 3,211,264

__global__ __launch_bounds__(256) void owa_pool_kernel(
    const vf4* __restrict__ xin,
    const float* __restrict__ kw,
    vf4* __restrict__ out)
{
    const float k0 = kw[0], k1 = kw[1], k2 = kw[2], k3 = kw[3];

    int idx0 = blockIdx.x * blockDim.x + threadIdx.x;

    #pragma unroll
    for (int rep = 0; rep < PER_THREAD; ++rep) {
        int idx = idx0 + rep * STRIDE_;

        // decode output coordinate (channel-quad innermost)
        int c4 = idx & (C4_ - 1);
        int t  = idx >> 5;           // / C4_
        int pw = t % PW_;
        int t2 = t / PW_;
        int ph = t2 % PH_;
        int b  = t2 / PH_;

        // input row base in float4 units
        int row0 = ((b * H_ + 2 * ph) * W_ + 2 * pw) * C4_ + c4;
        int row1 = row0 + W_ * C4_;

        vf4 v0 = __builtin_nontemporal_load(&xin[row0]);
        vf4 v1 = __builtin_nontemporal_load(&xin[row0 + C4_]);
        vf4 v2 = __builtin_nontemporal_load(&xin[row1]);
        vf4 v3 = __builtin_nontemporal_load(&xin[row1 + C4_]);

        vf4 r;
        // 4-element descending sort network (5 comparators) + weighted sum
        #pragma unroll
        for (int comp = 0; comp < 4; ++comp) {
            float a0 = v0[comp], a1 = v1[comp], a2 = v2[comp], a3 = v3[comp];
            float hi01 = fmaxf(a0, a1), lo01 = fminf(a0, a1);
            float hi23 = fmaxf(a2, a3), lo23 = fminf(a2, a3);
            float s0 = fmaxf(hi01, hi23), m  = fminf(hi01, hi23);
            float M  = fmaxf(lo01, lo23), s3 = fminf(lo01, lo23);
            float s1 = fmaxf(m, M), s2 = fminf(m, M);
            r[comp] = k0 * s0 + k1 * s1 + k2 * s2 + k3 * s3;
        }

        __builtin_nontemporal_store(r, &out[idx]);
    }
}

extern "C" void kernel_launch(void* const* d_in, const int* in_sizes, int n_in,
                              void* d_out, int out_size, void* d_ws, size_t ws_size,
                              hipStream_t stream) {
    const vf4* xin = (const vf4*)d_in[0];
    const float* kw = (const float*)d_in[1];
    vf4* out = (vf4*)d_out;

    int threads_total = N4_ / PER_THREAD;
    int blocks = (threads_total + 255) / 256;   // 12,544 blocks
    owa_pool_kernel<<<blocks, 256, 0, stream>>>(xin, kw, out);
}